// Round 11
// baseline (81.501 us; speedup 1.0000x reference)
//
#include <hip/hip_runtime.h>
#include <hip/hip_bf16.h>

// SpikingPolicyNet: B=8192, D_in=256, H=1024, D_out=64, T=15, TAU=20, V_TH=1
//
// Pipeline:
//  K0 : W2 -> W2cb (bf16 W2^T, row 1024 zeroed = sentinel for padded entries)
//  K1 : bf16-MFMA x@W1.T; epilogue folds b1 and emits the closed-form spike
//       interval k = ceil(log2(1-1/I)/log2(0.95)) as byte plane kb[b][j]
//       (layer-1 spikes at t = k,2k,...; I1 time-invariant).
//  K2 : block-per-row. LDS bucket-sort: regions r=0..7 for k=8..15, r=8 for
//       all k<=7 (k kept in entry bits 12..15). Every region min-width 4,
//       sentinel-padded -> its first quad ALWAYS exists -> straight-line
//       PRIME/CONSUME software pipeline (two groups, ~16-20 global loads in
//       flight before any consume; the R10 15-loop chain-restart killer).
//       Certificate: M = b2 + Ps + relu(max G8..15) >= max_t I2_t
//       (t<=7: I2 <= b2+Ps; t>=8: t's only divisor >=8 is t). M<=0.999
//       (margin >> fp drift) + induction v2_t <= M(1-.95^t) proves zero s2
//       spikes -> out = bout bit-exact (absmax==0 R1-R10 incl fp32 R1).
//       Cert-failing rows (rare) run the exact per-step re-gather inline
//       (divisor sets via compile-time divmask bitmasks).

#define B_SZ   8192
#define D_IN   256
#define H_SZ   1024
#define D_OUT  64
#define T_STEPS 15
#define SKIP_THR 0.999f

typedef __attribute__((ext_vector_type(8))) short short8;
typedef __attribute__((ext_vector_type(4))) float f32x4;

static __device__ __forceinline__ unsigned int pk_bf16(float lo, float hi) {
    return (__builtin_bit_cast(unsigned int, hi) & 0xffff0000u) |
           (__builtin_bit_cast(unsigned int, lo) >> 16);
}
static __device__ __forceinline__ f32x4 unp4(uint2 w) {
    f32x4 r;
    r.x = __builtin_bit_cast(float, w.x << 16);
    r.y = __builtin_bit_cast(float, w.x & 0xffff0000u);
    r.z = __builtin_bit_cast(float, w.y << 16);
    r.w = __builtin_bit_cast(float, w.y & 0xffff0000u);
    return r;
}
static __device__ __forceinline__ f32x4 relu4(f32x4 a) {
    a.x = fmaxf(a.x, 0.f); a.y = fmaxf(a.y, 0.f);
    a.z = fmaxf(a.z, 0.f); a.w = fmaxf(a.w, 0.f);
    return a;
}
static __device__ __forceinline__ f32x4 vmax4(f32x4 a, f32x4 b) {
    f32x4 r;
    r.x = fmaxf(a.x, b.x); r.y = fmaxf(a.y, b.y);
    r.z = fmaxf(a.z, b.z); r.w = fmaxf(a.w, b.w);
    return r;
}
__host__ __device__ constexpr unsigned divmask(int t) {   // bit k set iff k | t
    unsigned m = 0;
    for (int k = 1; k <= 15; ++k) if (t % k == 0) m |= 1u << k;
    return m;
}

// ---------------------------------------------------------------- K0: W2 -> W2cb (+zero pad row)
__global__ __launch_bounds__(256) void k0_transpose(const float* __restrict__ W2,
                                                    unsigned short* __restrict__ W2cb) {
    __shared__ float tile[32][33];
    const int bx = blockIdx.x * 32;
    const int by = blockIdx.y * 32;
    const int tx = threadIdx.x;
    const int ty = threadIdx.y;
    #pragma unroll
    for (int i = ty; i < 32; i += 8)
        tile[i][tx] = W2[(by + i) * H_SZ + bx + tx];
    __syncthreads();
    #pragma unroll
    for (int i = ty; i < 32; i += 8)
        W2cb[(size_t)(bx + i) * H_SZ + by + tx] =
            (unsigned short)(__builtin_bit_cast(unsigned int, tile[tx][i]) >> 16);
    if (blockIdx.x == 0 && blockIdx.y == 0) {                   // zero sentinel row 1024
        const int t = ty * 32 + tx;
        #pragma unroll
        for (int i = 0; i < 4; ++i)
            W2cb[(size_t)H_SZ * H_SZ + i * 256 + t] = 0;
    }
}

// ---------------------------------------------------------------- K1: interval byte-plane from x@W1.T+b1
__global__ __launch_bounds__(256) void k1_mfma(const float* __restrict__ A,
                                               const float* __restrict__ Bw,
                                               const float* __restrict__ b1,
                                               unsigned char* __restrict__ kb) {
    __shared__ unsigned int As4[2048];   // 128 rows x 32 bf16, 16B-chunk XOR swizzle
    __shared__ unsigned int Bs4[2048];
    const int tid  = threadIdx.x;
    const int m0   = blockIdx.x * 128;
    const int n0   = blockIdx.y * 128;
    const int lane = tid & 63;
    const int wid  = tid >> 6;
    const int wr   = wid >> 1, wc = wid & 1;

    const int row0 = tid >> 2;
    const int row1 = row0 + 64;
    const int q0   = tid & 3;

    f32x4 acc[4][4] = {};
    float4 s0[8], s1[8];

    auto LOAD = [&](float4* s, int kbk) {
        const float* pa0 = A  + (m0 + row0) * D_IN + kbk + q0 * 8;
        const float* pa1 = A  + (m0 + row1) * D_IN + kbk + q0 * 8;
        const float* pb0 = Bw + (n0 + row0) * D_IN + kbk + q0 * 8;
        const float* pb1 = Bw + (n0 + row1) * D_IN + kbk + q0 * 8;
        s[0] = *(const float4*)pa0; s[1] = *(const float4*)(pa0 + 4);
        s[2] = *(const float4*)pa1; s[3] = *(const float4*)(pa1 + 4);
        s[4] = *(const float4*)pb0; s[5] = *(const float4*)(pb0 + 4);
        s[6] = *(const float4*)pb1; s[7] = *(const float4*)(pb1 + 4);
    };
    auto WRITE = [&](const float4* s) {
        const int i0 = row0 * 16 + (q0 ^ ((row0 >> 1) & 3)) * 4;
        const int i1 = row1 * 16 + (q0 ^ ((row1 >> 1) & 3)) * 4;
        *(uint4*)&As4[i0] = make_uint4(pk_bf16(s[0].x, s[0].y), pk_bf16(s[0].z, s[0].w),
                                       pk_bf16(s[1].x, s[1].y), pk_bf16(s[1].z, s[1].w));
        *(uint4*)&As4[i1] = make_uint4(pk_bf16(s[2].x, s[2].y), pk_bf16(s[2].z, s[2].w),
                                       pk_bf16(s[3].x, s[3].y), pk_bf16(s[3].z, s[3].w));
        *(uint4*)&Bs4[i0] = make_uint4(pk_bf16(s[4].x, s[4].y), pk_bf16(s[4].z, s[4].w),
                                       pk_bf16(s[5].x, s[5].y), pk_bf16(s[5].z, s[5].w));
        *(uint4*)&Bs4[i1] = make_uint4(pk_bf16(s[6].x, s[6].y), pk_bf16(s[6].z, s[6].w),
                                       pk_bf16(s[7].x, s[7].y), pk_bf16(s[7].z, s[7].w));
    };
    auto COMPUTE = [&]() {
        short8 afr[4], bfr[4];
        const int q  = lane >> 4;
        const int lr = lane & 15;
        #pragma unroll
        for (int mf = 0; mf < 4; ++mf) {
            const int ra = wr * 64 + mf * 16 + lr;
            afr[mf] = *(const short8*)&As4[ra * 16 + (q ^ ((ra >> 1) & 3)) * 4];
            const int rb = wc * 64 + mf * 16 + lr;
            bfr[mf] = *(const short8*)&Bs4[rb * 16 + (q ^ ((rb >> 1) & 3)) * 4];
        }
        #pragma unroll
        for (int mf = 0; mf < 4; ++mf)
            #pragma unroll
            for (int nf = 0; nf < 4; ++nf)
                acc[mf][nf] = __builtin_amdgcn_mfma_f32_16x16x32_bf16(
                    afr[mf], bfr[nf], acc[mf][nf], 0, 0, 0);
    };

    LOAD(s0, 0);
    for (int kk = 0; kk < D_IN; kk += 64) {
        if (kk + 32 < D_IN) LOAD(s1, kk + 32);
        __syncthreads();
        WRITE(s0);
        __syncthreads();
        COMPUTE();
        if (kk + 64 < D_IN) LOAD(s0, kk + 64);
        __syncthreads();
        WRITE(s1);
        __syncthreads();
        COMPUTE();
    }

    // Epilogue: I = acc + b1[col]; k = ceil(log2(1-1/I)*-13.5134035), 0 = none.
    const int lr = lane & 15;
    const int qq = lane >> 4;
    float b1v[4];
    #pragma unroll
    for (int nf = 0; nf < 4; ++nf) b1v[nf] = b1[n0 + wc * 64 + nf * 16 + lr];

    #pragma unroll
    for (int mf = 0; mf < 4; ++mf) {
        const int rbase = m0 + wr * 64 + mf * 16 + qq * 4;
        #pragma unroll
        for (int nf = 0; nf < 4; ++nf) {
            const int c = n0 + wc * 64 + nf * 16 + lr;
            #pragma unroll
            for (int r = 0; r < 4; ++r) {
                const float I = acc[mf][nf][r] + b1v[nf];
                int k = 0;
                if (I > 1.8632055f) {
                    const float l2 = __builtin_amdgcn_logf(1.0f - __builtin_amdgcn_rcpf(I));
                    int kc = (int)__builtin_ceilf(l2 * -13.5134035f);
                    k = kc < 1 ? 1 : (kc > 15 ? 15 : kc);
                }
                kb[(size_t)(rbase + r) * H_SZ + c] = (unsigned char)k;
            }
        }
    }
}

// ---------------------------------------------------------------- K2: pipelined bucket gather
// PRIME(R): issue entry-read + 4 weight loads for region R's first quad.
#define PRIME(R)                                                              \
    const uint2 eq##R = *(const uint2*)&ent[stt[R]];                          \
    const int sa##R = __builtin_amdgcn_readfirstlane((int)eq##R.x);           \
    const int sb##R = __builtin_amdgcn_readfirstlane((int)eq##R.y);           \
    const uint2 wa##R = *(const uint2*)(W2cb + ((size_t)(sa##R & 0xfff) << 10) + jc);         \
    const uint2 wb##R = *(const uint2*)(W2cb + ((size_t)((sa##R >> 16) & 0xfff) << 10) + jc); \
    const uint2 wg##R = *(const uint2*)(W2cb + ((size_t)(sb##R & 0xfff) << 10) + jc);         \
    const uint2 wd##R = *(const uint2*)(W2cb + ((size_t)((sb##R >> 16) & 0xfff) << 10) + jc);

#define CONSUME(R, GV)                                                        \
    GV += unp4(wa##R); GV += unp4(wb##R); GV += unp4(wg##R); GV += unp4(wd##R);

#define CONSUME_RELU(R)                                                       \
    Ps += relu4(unp4(wa##R)); Ps += relu4(unp4(wb##R));                       \
    Ps += relu4(unp4(wg##R)); Ps += relu4(unp4(wd##R));

// generic quad over runtime index (remainders + rare path)
#define GQUAD(IDX, BODY)                                                      \
    { const uint2 eq = *(const uint2*)&ent[IDX];                              \
      const int sa = __builtin_amdgcn_readfirstlane((int)eq.x);               \
      const int sb = __builtin_amdgcn_readfirstlane((int)eq.y);               \
      const uint2 qa = *(const uint2*)(W2cb + ((size_t)(sa & 0xfff) << 10) + jc);         \
      const uint2 qb = *(const uint2*)(W2cb + ((size_t)((sa >> 16) & 0xfff) << 10) + jc); \
      const uint2 qc = *(const uint2*)(W2cb + ((size_t)(sb & 0xfff) << 10) + jc);         \
      const uint2 qd = *(const uint2*)(W2cb + ((size_t)((sb >> 16) & 0xfff) << 10) + jc); \
      BODY }

#define REM(R, GV)                                                            \
    for (int i = stt[R] + 4; i < stt[(R) + 1]; i += 4)                        \
        GQUAD(i, GV += unp4(qa); GV += unp4(qb); GV += unp4(qc); GV += unp4(qd);)

#define TBIG(T)                                                               \
    for (int i = stt[(T) - 8]; i < stt[(T) - 7]; i += 4)                      \
        GQUAD(i, i2 += unp4(qa); i2 += unp4(qb); i2 += unp4(qc); i2 += unp4(qd);)

#define TSMALL(T)                                                             \
    { constexpr unsigned dm = divmask(T);                                     \
      for (int i = stt[8]; i < stt[9]; i += 2) {                              \
          const int ee = __builtin_amdgcn_readfirstlane(                      \
              (int)*(const unsigned int*)&ent[i]);                            \
          const int j1 = ee & 0xfff, k1 = (ee >> 12) & 15;                    \
          const int j2 = (ee >> 16) & 0xfff, k2 = (ee >> 28) & 15;            \
          if ((dm >> k1) & 1) {                                               \
              const uint2 w = *(const uint2*)(W2cb + ((size_t)j1 << 10) + jc);\
              i2 += unp4(w); }                                                \
          if ((dm >> k2) & 1) {                                               \
              const uint2 w = *(const uint2*)(W2cb + ((size_t)j2 << 10) + jc);\
              i2 += unp4(w); }                                                \
      } }

#define STEP                                                                  \
    { v2 = v2 * 0.95f + i2 * 0.05f;                                           \
      if (v2.x > 1.0f) { v2.x = 0.f; ++c0; }                                  \
      if (v2.y > 1.0f) { v2.y = 0.f; ++c1; }                                  \
      if (v2.z > 1.0f) { v2.z = 0.f; ++c2; }                                  \
      if (v2.w > 1.0f) { v2.w = 0.f; ++c3; } }

__global__ __launch_bounds__(256, 4) void k2_snn(const unsigned char* __restrict__ kb,
                                                 const unsigned short* __restrict__ W2cb,
                                                 const float* __restrict__ b2,
                                                 const float* __restrict__ Wout,
                                                 const float* __restrict__ bout,
                                                 float* __restrict__ out) {
    const int b   = blockIdx.x;
    const int tid = threadIdx.x;
    const int jc  = tid * 4;

    __shared__ int cnt[16];                  // [0] = small (k<=7), [8..15] = big
    __shared__ int st[10];                   // region starts, regions 0..8 (+end)
    __shared__ int curs[9];
    __shared__ unsigned short ent[1120];     // entry = j | (k<<12); sentinel j=1024,k=1
    __shared__ int flag;
    __shared__ int tot;
    __shared__ float rrow[H_SZ];

    if (tid < 16) { cnt[tid] = 0; if (tid == 0) { flag = 0; tot = 0; } }
    const unsigned int kw = *(const unsigned int*)(kb + (size_t)b * H_SZ + jc);
    const f32x4 b2q = *(const f32x4*)&b2[jc];
    __syncthreads();

    if (kw) {
        #pragma unroll
        for (int u = 0; u < 4; ++u) {
            const unsigned int ku = (kw >> (8 * u)) & 0xffu;
            if (ku) atomicAdd(&cnt[(ku >= 8) ? (int)ku : 0], 1);
        }
    }
    __syncthreads();
    if (tid < 10) {                          // parallel prefix over 9 regions
        int s = 0;
        for (int r = 0; r < tid; ++r) {
            const int c = (r < 8) ? cnt[8 + r] : cnt[0];
            int w = (c + 3) & ~3;
            if (w < 4) w = 4;                // min-width 4: first quad always exists
            s += w;
        }
        st[tid] = s;
        if (tid < 9) curs[tid] = s;
    }
    __syncthreads();
    if (kw) {
        #pragma unroll
        for (int u = 0; u < 4; ++u) {
            const unsigned int ku = (kw >> (8 * u)) & 0xffu;
            if (ku) {
                const int r = (ku >= 8) ? (int)ku - 8 : 8;
                const int p = atomicAdd(&curs[r], 1);
                ent[p] = (unsigned short)((jc + u) | (ku << 12));
            }
        }
    }
    if (tid < 9) {                           // sentinel-pad region tails
        const int c = (tid < 8) ? cnt[8 + tid] : cnt[0];
        for (int p = st[tid] + c; p < st[tid + 1]; ++p)
            ent[p] = (unsigned short)(H_SZ | (1u << 12));   // zero row, k=1
    }
    __syncthreads();

    int stt[10];
    #pragma unroll
    for (int r = 0; r < 10; ++r) stt[r] = __builtin_amdgcn_readfirstlane(st[r]);

    f32x4 G8 = {0,0,0,0}, G9 = {0,0,0,0}, G10 = {0,0,0,0}, G11 = {0,0,0,0};
    f32x4 G12 = {0,0,0,0}, G13 = {0,0,0,0}, G14 = {0,0,0,0}, G15 = {0,0,0,0};
    f32x4 Ps = {0,0,0,0};

    {   // group A: regions 0..3 (k=8..11) primed together (16 loads in flight)
        PRIME(0) PRIME(1) PRIME(2) PRIME(3)
        CONSUME(0, G8) CONSUME(1, G9) CONSUME(2, G10) CONSUME(3, G11)
    }
    {   // group B: regions 4..8 (k=12..15 + small) primed together (20 loads)
        PRIME(4) PRIME(5) PRIME(6) PRIME(7) PRIME(8)
        CONSUME(4, G12) CONSUME(5, G13) CONSUME(6, G14) CONSUME(7, G15)
        CONSUME_RELU(8)
    }
    // remainders (only buckets with >4 entries; typically k=13..15)
    REM(0, G8)  REM(1, G9)  REM(2, G10) REM(3, G11)
    REM(4, G12) REM(5, G13) REM(6, G14) REM(7, G15)
    for (int i = stt[8] + 4; i < stt[9]; i += 4)
        GQUAD(i, Ps += relu4(unp4(qa)); Ps += relu4(unp4(qb));
                 Ps += relu4(unp4(qc)); Ps += relu4(unp4(qd));)

    // ---- certificate: M >= max_t I2_t (slack = Ps only)
    f32x4 gm = vmax4(G8, G9);
    gm = vmax4(gm, G10); gm = vmax4(gm, G11); gm = vmax4(gm, G12);
    gm = vmax4(gm, G13); gm = vmax4(gm, G14); gm = vmax4(gm, G15);
    const float M0 = b2q.x + Ps.x + fmaxf(gm.x, 0.f);
    const float M1 = b2q.y + Ps.y + fmaxf(gm.y, 0.f);
    const float M2 = b2q.z + Ps.z + fmaxf(gm.z, 0.f);
    const float M3 = b2q.w + Ps.w + fmaxf(gm.w, 0.f);
    if ((M0 > SKIP_THR) || (M1 > SKIP_THR) || (M2 > SKIP_THR) || (M3 > SKIP_THR))
        atomicOr(&flag, 1);
    __syncthreads();

    if (flag == 0) {                         // proven spike-free: out = bout (bit-exact)
        if (tid < D_OUT) out[(size_t)b * D_OUT + tid] = bout[tid];
        return;
    }

    // ---- rare exact path: per-step re-gather (static divisor structure)
    f32x4 v2 = {0,0,0,0};
    int c0 = 0, c1 = 0, c2 = 0, c3 = 0;
    { f32x4 i2 = b2q; TSMALL(1) STEP }
    { f32x4 i2 = b2q; TSMALL(2) STEP }
    { f32x4 i2 = b2q; TSMALL(3) STEP }
    { f32x4 i2 = b2q; TSMALL(4) STEP }
    { f32x4 i2 = b2q; TSMALL(5) STEP }
    { f32x4 i2 = b2q; TSMALL(6) STEP }
    { f32x4 i2 = b2q; TSMALL(7) STEP }
    { f32x4 i2 = b2q; TBIG(8)  TSMALL(8)  STEP }
    { f32x4 i2 = b2q; TBIG(9)  TSMALL(9)  STEP }
    { f32x4 i2 = b2q; TBIG(10) TSMALL(10) STEP }
    { f32x4 i2 = b2q; TBIG(11) TSMALL(11) STEP }
    { f32x4 i2 = b2q; TBIG(12) TSMALL(12) STEP }
    { f32x4 i2 = b2q; TBIG(13) TSMALL(13) STEP }
    { f32x4 i2 = b2q; TBIG(14) TSMALL(14) STEP }
    { f32x4 i2 = b2q; TBIG(15) TSMALL(15) STEP }

    const int my = c0 + c1 + c2 + c3;
    if (my) atomicAdd(&tot, my);
    __syncthreads();

    if (tot == 0) {                          // simulated exactly, no s2 spikes
        if (tid < D_OUT) out[(size_t)b * D_OUT + tid] = bout[tid];
        return;
    }

    rrow[jc + 0] = (float)c0 / 15.0f;
    rrow[jc + 1] = (float)c1 / 15.0f;
    rrow[jc + 2] = (float)c2 / 15.0f;
    rrow[jc + 3] = (float)c3 / 15.0f;
    __syncthreads();
    if (tid < D_OUT) {
        float a = bout[tid];
        const float* wrow = Wout + (size_t)tid * H_SZ;
        for (int j = 0; j < H_SZ; ++j) a = fmaf(rrow[j], wrow[j], a);
        out[(size_t)b * D_OUT + tid] = a;
    }
}

// ---------------------------------------------------------------- launch
extern "C" void kernel_launch(void* const* d_in, const int* in_sizes, int n_in,
                              void* d_out, int out_size, void* d_ws, size_t ws_size,
                              hipStream_t stream) {
    const float* x    = (const float*)d_in[0];
    const float* W1   = (const float*)d_in[1];
    const float* b1   = (const float*)d_in[2];
    const float* W2   = (const float*)d_in[3];
    const float* b2   = (const float*)d_in[4];
    const float* Wout = (const float*)d_in[5];
    const float* bout = (const float*)d_in[6];
    float* out = (float*)d_out;

    char* ws = (char*)d_ws;
    unsigned short* W2cb = (unsigned short*)(ws);              // 2 MB + 2 KB pad row
    unsigned char*  kbuf = (unsigned char*)(ws + (8 << 20));   // 8 MB intervals

    k0_transpose<<<dim3(H_SZ / 32, H_SZ / 32), dim3(32, 8), 0, stream>>>(W2, W2cb);
    k1_mfma<<<dim3(B_SZ / 128, H_SZ / 128), 256, 0, stream>>>(x, W1, b1, kbuf);
    k2_snn<<<B_SZ, 256, 0, stream>>>(kbuf, W2cb, b2, Wout, bout, out);
}